// Round 11
// baseline (1273.849 us; speedup 1.0000x reference)
//
#include <hip/hip_runtime.h>
#include <hip/hip_bf16.h>
#include <cfloat>
#include <cstdint>

// ---------------------------------------------------------------------------
// RPN pipeline (B=1): conv3d(256->512,3x3x3,SAME)+ReLU -> heads -> proposals
// Round-11: r10 conv + (1) A-fragment register DOUBLE-BUFFER (load stage s+1
// during stage s compute — kills the post-barrier L2-latency stall) and
// (2) bit-trick B split (trunc + v_perm pack, exact residual <=2^-24|x|,
// ~88 VALU/stage vs ~190 RNE chain). B LDS layout and MFMA accumulation
// order unchanged from r10 (absmax 0.0).
// ---------------------------------------------------------------------------

#define T_DIM 16
#define H_DIM 32
#define W_DIM 32
#define NVOX  (T_DIM*H_DIM*W_DIM)   // 16384
#define HW    (H_DIM*W_DIM)         // 1024
#define CIN   256
#define COUT  512
#define PRE_NMS 1000
#define POST_NMS 128
#define NMS_TH 0.7f

typedef __attribute__((ext_vector_type(8))) short v8s;
typedef __attribute__((ext_vector_type(4))) float v4f;
typedef __attribute__((ext_vector_type(4))) int v4i;

#define MFMA_B16(A,B,C) __builtin_amdgcn_mfma_f32_16x16x32_bf16(A,B,C,0,0,0)

__device__ __forceinline__ short f2bf(float x) {
    unsigned u = __float_as_uint(x);
    u += 0x7FFFu + ((u >> 16) & 1u);
    return (short)(u >> 16);
}
__device__ __forceinline__ float bf2f(short s) {
    return __uint_as_float(((unsigned)(unsigned short)s) << 16);
}

__constant__ float c_ws[3] = {23.f, 16.f, 11.f};
__constant__ float c_hs[3] = {12.f, 16.f, 22.f};
__constant__ float c_sc[3] = {4.f, 8.f, 16.f};
__constant__ float c_depth[3] = {16.f, 8.f, 4.f};

// ---------------------------------------------------------------------------
// Weight split, FRAGMENT-MAJOR: Af[((tap*32 + ko)*512 + o)*8 + c7], c=ko*8+c7.
__global__ void k_split_w(const float* __restrict__ W, short* __restrict__ A0,
                          short* __restrict__ A1, short* __restrict__ A2) {
    int i = blockIdx.x * 256 + threadIdx.x;   // over 27*32*512*8 = 3538944
    int c7 = i & 7;
    int o = (i >> 3) & 511;
    int ko = (i >> 12) & 31;
    int tap = i >> 17;
    int c = ko * 8 + c7;
    float x = W[(o * 256 + c) * 27 + tap];
    short h = f2bf(x); float r = x - bf2f(h);
    short m = f2bf(r); float r2 = r - bf2f(m);
    short l = f2bf(r2);
    A0[i] = h; A1[i] = m; A2[i] = l;
}

__global__ void k_build_wcomb(const float* __restrict__ Wcls, const float* __restrict__ Wbb,
                              float* __restrict__ Wc) {
    int i = blockIdx.x * 256 + threadIdx.x;   // over 512*256
    int o = i & 255;
    int c = i >> 8;
    float v = 0.f;
    if (o < 54) v = Wcls[o * 512 + c];
    else if (o < 216) v = Wbb[(o - 54) * 512 + c];
    Wc[i] = v;
}

// ---------------------------------------------------------------------------
// bit-trick split of 2 floats -> 3 packed bf16-pair ints (low = X0, high = X1)
// h = top16(x) [trunc]; r = x-h exact; m = top16(r); l = top16(r-m).
// residual <= 2^-24|x| (same class as RNE 3-way split, verified r7/r10).
#define SPLIT2(X0, X1, OH, OM, OL) {                                          \
    unsigned u0_ = __float_as_uint(X0), u1_ = __float_as_uint(X1);            \
    OH = (int)__builtin_amdgcn_perm(u1_, u0_, 0x07060302u);                   \
    float h0_ = __uint_as_float(u0_ & 0xFFFF0000u);                           \
    float h1_ = __uint_as_float(u1_ & 0xFFFF0000u);                           \
    float r0_ = (X0) - h0_, r1_ = (X1) - h1_;                                 \
    unsigned v0_ = __float_as_uint(r0_), v1_ = __float_as_uint(r1_);          \
    OM = (int)__builtin_amdgcn_perm(v1_, v0_, 0x07060302u);                   \
    float m0_ = __uint_as_float(v0_ & 0xFFFF0000u);                           \
    float m1_ = __uint_as_float(v1_ & 0xFFFF0000u);                           \
    float s0_ = r0_ - m0_, s1_ = r1_ - m1_;                                   \
    OL = (int)__builtin_amdgcn_perm(__float_as_uint(s1_),                     \
                                    __float_as_uint(s0_), 0x07060302u);       \
}

#define CV_SHIFT(TAP) {                                                       \
    int kt_ = (TAP) / 9 - 1, kh_ = ((TAP) / 3) % 3 - 1, kw_ = (TAP) % 3 - 1;  \
    int tt_ = bt + kt_, hh_ = bh + kh_, ww_ = bw + kw_;                       \
    bVal = ((unsigned)tt_ < 16u) && ((unsigned)hh_ < 32u) && ((unsigned)ww_ < 32u); \
    bOff = bVal ? ((tt_ << 10) + (hh_ << 5) + ww_) : 0;                       \
}

// prefetch B: 16 fp32 at k = CK + skh*16 + j, v-row sa_o (tap-shifted), split
#define CV_LOAD_B(CK) {                                                       \
    const float* ip_ = I + ((size_t)((CK) + skh * 16) << 14) + bOff;          \
    float x0_  = bVal ? ip_[0]        : 0.f;                                  \
    float x1_  = bVal ? ip_[1 << 14]  : 0.f;                                  \
    float x2_  = bVal ? ip_[2 << 14]  : 0.f;                                  \
    float x3_  = bVal ? ip_[3 << 14]  : 0.f;                                  \
    float x4_  = bVal ? ip_[4 << 14]  : 0.f;                                  \
    float x5_  = bVal ? ip_[5 << 14]  : 0.f;                                  \
    float x6_  = bVal ? ip_[6 << 14]  : 0.f;                                  \
    float x7_  = bVal ? ip_[7 << 14]  : 0.f;                                  \
    float x8_  = bVal ? ip_[8 << 14]  : 0.f;                                  \
    float x9_  = bVal ? ip_[9 << 14]  : 0.f;                                  \
    float x10_ = bVal ? ip_[10 << 14] : 0.f;                                  \
    float x11_ = bVal ? ip_[11 << 14] : 0.f;                                  \
    float x12_ = bVal ? ip_[12 << 14] : 0.f;                                  \
    float x13_ = bVal ? ip_[13 << 14] : 0.f;                                  \
    float x14_ = bVal ? ip_[14 << 14] : 0.f;                                  \
    float x15_ = bVal ? ip_[15 << 14] : 0.f;                                  \
    int h01,h23,h45,h67,m01,m23,m45,m67,l01,l23,l45,l67;                      \
    SPLIT2(x0_,  x1_,  h01, m01, l01);                                        \
    SPLIT2(x2_,  x3_,  h23, m23, l23);                                        \
    SPLIT2(x4_,  x5_,  h45, m45, l45);                                        \
    SPLIT2(x6_,  x7_,  h67, m67, l67);                                        \
    pbh0 = (v4i){h01, h23, h45, h67};                                         \
    pbm0 = (v4i){m01, m23, m45, m67};                                         \
    pbl0 = (v4i){l01, l23, l45, l67};                                         \
    SPLIT2(x8_,  x9_,  h01, m01, l01);                                        \
    SPLIT2(x10_, x11_, h23, m23, l23);                                        \
    SPLIT2(x12_, x13_, h45, m45, l45);                                        \
    SPLIT2(x14_, x15_, h67, m67, l67);                                        \
    pbh1 = (v4i){h01, h23, h45, h67};                                         \
    pbm1 = (v4i){m01, m23, m45, m67};                                         \
    pbl1 = (v4i){l01, l23, l45, l67};                                         \
}

#define DECL_ASET(P) v8s P##h0, P##h1, P##h2, P##h3, P##m0, P##m1, P##m2,     \
                         P##m3, P##l0, P##l1, P##l2, P##l3;

#define LOAD_ASET(P, S) {                                                     \
    const size_t aB_ = (((size_t)((S) >> 3) * 32 + (((S) & 7) << 2)) << 12) + aLane; \
    P##h0 = *(const v8s*)(A0 + aB_);       P##h1 = *(const v8s*)(A0 + aB_ + 128); \
    P##h2 = *(const v8s*)(A0 + aB_ + 256); P##h3 = *(const v8s*)(A0 + aB_ + 384); \
    P##m0 = *(const v8s*)(A1 + aB_);       P##m1 = *(const v8s*)(A1 + aB_ + 128); \
    P##m2 = *(const v8s*)(A1 + aB_ + 256); P##m3 = *(const v8s*)(A1 + aB_ + 384); \
    P##l0 = *(const v8s*)(A2 + aB_);       P##l1 = *(const v8s*)(A2 + aB_ + 128); \
    P##l2 = *(const v8s*)(A2 + aB_ + 256); P##l3 = *(const v8s*)(A2 + aB_ + 384); \
}

#define COMPUTE(P) {                                                          \
    _Pragma("unroll")                                                         \
    for (int j = 0; j < 4; ++j) {                                             \
        v8s bb = *(const v8s*)(&Bsh[0][uB + j * 16]);                         \
        v8s bm = *(const v8s*)(&Bsh[1][uB + j * 16]);                         \
        v8s bl = *(const v8s*)(&Bsh[2][uB + j * 16]);                         \
        v4f a;                                                                \
        a = acc[0][j];                                                        \
        a = MFMA_B16(P##h0, bb, a); a = MFMA_B16(P##h0, bm, a);               \
        a = MFMA_B16(P##m0, bb, a); a = MFMA_B16(P##h0, bl, a);               \
        a = MFMA_B16(P##m0, bm, a); a = MFMA_B16(P##l0, bb, a);               \
        acc[0][j] = a;                                                        \
        a = acc[1][j];                                                        \
        a = MFMA_B16(P##h1, bb, a); a = MFMA_B16(P##h1, bm, a);               \
        a = MFMA_B16(P##m1, bb, a); a = MFMA_B16(P##h1, bl, a);               \
        a = MFMA_B16(P##m1, bm, a); a = MFMA_B16(P##l1, bb, a);               \
        acc[1][j] = a;                                                        \
        a = acc[2][j];                                                        \
        a = MFMA_B16(P##h2, bb, a); a = MFMA_B16(P##h2, bm, a);               \
        a = MFMA_B16(P##m2, bb, a); a = MFMA_B16(P##h2, bl, a);               \
        a = MFMA_B16(P##m2, bm, a); a = MFMA_B16(P##l2, bb, a);               \
        acc[2][j] = a;                                                        \
        a = acc[3][j];                                                        \
        a = MFMA_B16(P##h3, bb, a); a = MFMA_B16(P##h3, bm, a);               \
        a = MFMA_B16(P##m3, bb, a); a = MFMA_B16(P##h3, bl, a);               \
        a = MFMA_B16(P##m3, bm, a); a = MFMA_B16(P##l3, bb, a);               \
        acc[3][j] = a;                                                        \
    }                                                                         \
}

// one stage: commit B(s) to LDS, prefetch A(s+1) into NXT + B(s+1) into pb*,
// then compute with CUR.
#define CONV_STAGE(S, CUR, NXT) {                                             \
    __syncthreads();                                                          \
    Bsh[0][uW0] = pbh0; Bsh[0][uW1] = pbh1;                                   \
    Bsh[1][uW0] = pbm0; Bsh[1][uW1] = pbm1;                                   \
    Bsh[2][uW0] = pbl0; Bsh[2][uW1] = pbl1;                                   \
    __syncthreads();                                                          \
    {                                                                         \
        int s1_ = (S) + 1;                                                    \
        if (s1_ < 216) {                                                      \
            LOAD_ASET(NXT, s1_);                                              \
            if ((s1_ & 7) == 0) CV_SHIFT(s1_ >> 3);                           \
            CV_LOAD_B((s1_ & 7) << 5);                                        \
        }                                                                     \
    }                                                                         \
    COMPUTE(CUR);                                                             \
}

// MFMA conv3d: 128x128 block tile, 4 waves in 2x2 (each 64o x 64v), BK=32,
// B single-buffer LDS (r10 layout), A register-double-buffered global frags.
__global__ __launch_bounds__(256) void k_conv3d_mfma(
        const float* __restrict__ I, const short* __restrict__ A0,
        const short* __restrict__ A1, const short* __restrict__ A2,
        const float* __restrict__ bias, float* __restrict__ O) {
    __shared__ v4i Bsh[3][512];   // 24 KB
    const int tid = threadIdx.x;
    const int o0 = blockIdx.y * 128;
    const int v0 = blockIdx.x * 128;
    const int lane = tid & 63;
    const int wv = tid >> 6;
    const int quad = lane >> 4, m16 = lane & 15;
    const int wo = (wv >> 1) * 64;        // wave o-origin within tile
    const int wvx = (wv & 1) * 64;        // wave v-origin within tile

    // B staging: row sa_o = tid>>1 (0..127), k-half skh = tid&1
    const int sa_o = tid >> 1, skh = tid & 1;
    const int uW0 = (skh * 2) * 128 + sa_o;
    const int uW1 = (skh * 2 + 1) * 128 + sa_o;

    const int vbase = v0 + sa_o;
    const int bt = vbase >> 10, bh = (vbase >> 5) & 31, bw = vbase & 31;

    // B fragment read base: [quad*128 + wvx + j*16 + m16]
    const int uB = quad * 128 + wvx + m16;

    // A fragment global base offset (shorts): lane part
    const size_t aLane = ((size_t)(o0 + wo + m16) << 3) + ((size_t)quad << 12);

    v4f acc[4][4];
#pragma unroll
    for (int i = 0; i < 4; i++)
#pragma unroll
        for (int j = 0; j < 4; j++) acc[i][j] = (v4f){0.f, 0.f, 0.f, 0.f};

    int bOff, bVal;
    v4i pbh0, pbh1, pbm0, pbm1, pbl0, pbl1;
    DECL_ASET(wA);
    DECL_ASET(wB);

    CV_SHIFT(0);
    CV_LOAD_B(0);
    LOAD_ASET(wA, 0);

    for (int s = 0; s < 216; s += 2) {    // 27 taps * 8 ck-steps (BK=32)
        CONV_STAGE(s,     wA, wB);
        CONV_STAGE(s + 1, wB, wA);
    }

    // epilogue: per 16x16 tile, col = m16 (v), row = quad*4 + reg (o)
#pragma unroll
    for (int i = 0; i < 4; ++i) {
#pragma unroll
        for (int r = 0; r < 4; ++r) {
            int o = o0 + wo + i * 16 + quad * 4 + r;
            float bo = bias[o];
            float* dst = O + (size_t)o * NVOX + v0 + wvx + m16;
#pragma unroll
            for (int j = 0; j < 4; ++j)
                dst[j * 16] = fmaxf(acc[i][j][r] + bo, 0.f);
        }
    }
}

// ---------------------------------------------------------------------------
// logits3 GEMM: L[o][v] = sum_c Wc[c][o] * conv1[c][v], M=256 (padded), K=512, N=16384
__global__ __launch_bounds__(256) void k_gemm_logits3(const float* __restrict__ conv1,
                                                      const float* __restrict__ Wc,
                                                      float* __restrict__ L) {
    __shared__ float As[16][128];
    __shared__ float Bs[16][128];
    const int tid = threadIdx.x;
    const int o0 = blockIdx.y * 128;
    const int v0 = blockIdx.x * 128;
    const int ty = tid >> 4, tx = tid & 15;

    float acc[8][8];
#pragma unroll
    for (int i = 0; i < 8; i++)
#pragma unroll
        for (int j = 0; j < 8; j++) acc[i][j] = 0.f;

    for (int ck = 0; ck < 512; ck += 16) {
        __syncthreads();
#pragma unroll
        for (int r = 0; r < 2; ++r) {
            int f = tid + r * 256;
            int c_l = f >> 5, o4 = (f & 31) << 2;
            *(float4*)(&As[c_l][o4]) = *(const float4*)(Wc + ((size_t)(ck + c_l) << 8) + o0 + o4);
        }
#pragma unroll
        for (int r = 0; r < 2; ++r) {
            int f = tid + r * 256;
            int c_l = f >> 5, v4 = (f & 31) << 2;
            *(float4*)(&Bs[c_l][v4]) = *(const float4*)(conv1 + ((size_t)(ck + c_l) << 14) + v0 + v4);
        }
        __syncthreads();
#pragma unroll
        for (int k = 0; k < 16; ++k) {
            float a[8], b[8];
            *(float4*)(a)     = *(const float4*)(&As[k][ty * 4]);
            *(float4*)(a + 4) = *(const float4*)(&As[k][64 + ty * 4]);
            *(float4*)(b)     = *(const float4*)(&Bs[k][tx * 4]);
            *(float4*)(b + 4) = *(const float4*)(&Bs[k][64 + tx * 4]);
#pragma unroll
            for (int i = 0; i < 8; i++)
#pragma unroll
                for (int j = 0; j < 8; j++)
                    acc[i][j] = fmaf(a[i], b[j], acc[i][j]);
        }
    }
#pragma unroll
    for (int i = 0; i < 8; i++) {
        int orow = (i < 4) ? (ty * 4 + i) : (64 + ty * 4 + (i - 4));
        float* dst = L + (size_t)(o0 + orow) * NVOX + v0;
        *(float4*)(dst + tx * 4)      = *(const float4*)(&acc[i][0]);
        *(float4*)(dst + 64 + tx * 4) = *(const float4*)(&acc[i][4]);
    }
}

// ---------------------------------------------------------------------------
__global__ void k_sc3(const float* __restrict__ L, const float* __restrict__ b_cls,
                      float* __restrict__ sc3) {
    int i = blockIdx.x * 256 + threadIdx.x;   // 27648
    if (i >= 27 * HW) return;
    int a = i >> 10, hw = i & 1023;
    float b0 = b_cls[a], b1 = b_cls[27 + a];
    const float* L0 = L + (size_t)a * NVOX + hw;
    const float* L1 = L + (size_t)(27 + a) * NVOX + hw;
    float s = 0.f;
    for (int t = 0; t < T_DIM; t++) {
        float x0 = L0[t * HW] + b0, x1 = L1[t * HW] + b1;
        float m = fmaxf(x0, x1);
        float e0 = expf(x0 - m), e1 = expf(x1 - m);
        s += e1 / (e0 + e1);
    }
    sc3[hw * 27 + a] = s * (1.f / 16.f);
}

__global__ void k_dl3(const float* __restrict__ L, const float* __restrict__ b_bbox,
                      float* __restrict__ dl3) {
    int i = blockIdx.x * 256 + threadIdx.x;   // 165888
    if (i >= 162 * HW) return;
    int ch = i >> 10, hw = i & 1023;
    const float* Lr = L + (size_t)(54 + ch) * NVOX + hw;
    float s = 0.f;
    for (int t = 0; t < T_DIM; t++) s += Lr[t * HW];
    s = s * (1.f / 16.f) + b_bbox[ch];
    int a = ch / 6, d = ch - a * 6;
    dl3[((size_t)hw * 27 + a) * 6 + d] = s;
}

__global__ void k_feat2(const float* __restrict__ conv1, float* __restrict__ feat2) {
    int i = blockIdx.x * 256 + threadIdx.x;   // 524288
    int c = i >> 10, hw = i & 1023;
    const float* src = conv1 + (size_t)c * NVOX + hw;
    float s = 0.f;
    for (int t = 0; t < T_DIM; t++) s += src[t * HW];
    feat2[i] = s * (1.f / 16.f);
}

__global__ void k_gemm2d(const float* __restrict__ feat2, const float* __restrict__ Wcls16,
                         const float* __restrict__ Wbb16, float* __restrict__ L2) {
    int g = blockIdx.x * 256 + threadIdx.x;   // 55296
    int o = g >> 10, hw = g & 1023;
    const float* wrow = (o < 18) ? (Wcls16 + (size_t)o * 512) : (Wbb16 + (size_t)(o - 18) * 512);
    float s = 0.f;
    for (int c = 0; c < 512; c++) s = fmaf(wrow[c], feat2[(size_t)c * HW + hw], s);
    L2[(size_t)o * HW + hw] = s;
}

__global__ void k_sc2(const float* __restrict__ L2, const float* __restrict__ b_cls16,
                      float* __restrict__ sc2) {
    int i = blockIdx.x * 256 + threadIdx.x;   // 9216
    if (i >= 9 * HW) return;
    int a = i >> 10, hw = i & 1023;
    float x0 = L2[(size_t)a * HW + hw] + b_cls16[a];
    float x1 = L2[(size_t)(9 + a) * HW + hw] + b_cls16[9 + a];
    float m = fmaxf(x0, x1);
    float e0 = expf(x0 - m), e1 = expf(x1 - m);
    sc2[hw * 9 + a] = e1 / (e0 + e1);
}

__global__ void k_dl2(const float* __restrict__ L2, const float* __restrict__ b_bbox16,
                      float* __restrict__ dl2) {
    int i = blockIdx.x * 256 + threadIdx.x;   // 36864
    if (i >= 36 * HW) return;
    int ch = i >> 10, hw = i & 1023;
    float v = L2[(size_t)(18 + ch) * HW + hw] + b_bbox16[ch];
    int a = ch >> 2, d = ch & 3;
    dl2[((size_t)hw * 9 + a) * 4 + d] = v;
}

// ---------------------------------------------------------------------------
__device__ __forceinline__ unsigned mapf(float f) {
    unsigned u = __float_as_uint(f);
    return (u & 0x80000000u) ? ~u : (u | 0x80000000u);
}

__global__ __launch_bounds__(1024) void k_proposal(const float* __restrict__ im_info,
                                                   const float* __restrict__ sc3,
                                                   const float* __restrict__ dl3,
                                                   const float* __restrict__ sc2,
                                                   const float* __restrict__ dl2,
                                                   float* __restrict__ out) {
    const int branch = blockIdx.x;
    const int tid = threadIdx.x;
    const int A = (branch == 0) ? 27 : 9;
    const int nd = (branch == 0) ? 3 : 2;
    const float* scores = (branch == 0) ? sc3 : sc2;
    const float* deltas = (branch == 0) ? dl3 : dl2;
    const int K = PRE_NMS;
    const int ept = A;
    const int base = tid * ept;

    __shared__ unsigned hist[256];
    __shared__ unsigned long long keys[1024];
    __shared__ float bx[PRE_NMS][6];
    __shared__ int keep[POST_NMS];
    __shared__ unsigned wsum[16];
    __shared__ unsigned long long alive[16];
    __shared__ int sh_b, sh_next, bcast;

    // ================= radix-select =========================================
    unsigned prefix = 0;
    int rank = K;
    for (int shift = 24; shift >= 0; shift -= 8) {
        if (tid < 256) hist[tid] = 0;
        __syncthreads();
        const unsigned mask_hi = (shift == 24) ? 0u : (0xFFFFFFFFu << (shift + 8));
        for (int j = 0; j < ept; j++) {
            unsigned m = mapf(scores[base + j]);
            if ((m & mask_hi) == prefix)
                atomicAdd(&hist[(m >> shift) & 255], 1u);
        }
        __syncthreads();
        for (int d = 1; d < 256; d <<= 1) {
            unsigned add = 0;
            if (tid < 256 && tid + d < 256) add = hist[tid + d];
            __syncthreads();
            if (tid < 256) hist[tid] += add;
            __syncthreads();
        }
        if (tid < 256) {
            bool win = (hist[tid] >= (unsigned)rank) &&
                       (tid == 255 || hist[tid + 1] < (unsigned)rank);
            if (win) { sh_b = tid; sh_next = (tid == 255) ? 0 : (int)hist[tid + 1]; }
        }
        __syncthreads();
        prefix |= (unsigned)sh_b << shift;
        rank -= sh_next;
        __syncthreads();
    }
    const unsigned tau = prefix;

    // ================= compaction ===========================================
    int gt_c = 0, eq_c = 0;
    for (int j = 0; j < ept; j++) {
        unsigned m = mapf(scores[base + j]);
        gt_c += (m > tau);
        eq_c += (m == tau);
    }
    unsigned cnt = ((unsigned)gt_c << 16) | (unsigned)eq_c;
    const int lane = tid & 63, wid = tid >> 6;
    unsigned x = cnt;
    for (int d = 1; d < 64; d <<= 1) {
        unsigned y = __shfl_up(x, d);
        if (lane >= d) x += y;
    }
    if (lane == 63) wsum[wid] = x;
    __syncthreads();
    if (wid == 0) {
        unsigned w = (lane < 16) ? wsum[lane] : 0;
        for (int d = 1; d < 16; d <<= 1) {
            unsigned y = __shfl_up(w, d);
            if (lane >= d) w += y;
        }
        if (lane < 16) wsum[lane] = w;
    }
    __syncthreads();
    unsigned excl = x - cnt + (wid ? wsum[wid - 1] : 0);
    const int c1 = (int)(wsum[15] >> 16);
    int gi = (int)(excl >> 16);
    int ei = (int)(excl & 0xFFFFu);
    for (int j = 0; j < ept; j++) {
        int idx = base + j;
        unsigned m = mapf(scores[idx]);
        unsigned long long key = ((unsigned long long)m << 32) |
                                 (unsigned)(0xFFFFFFFFu - (unsigned)idx);
        if (m > tau) {
            keys[gi++] = key;
        } else if (m == tau) {
            if (c1 + ei < K) keys[c1 + ei] = key;
            ei++;
        }
    }
    if (tid < 1024 - K) keys[K + tid] = 0;
    __syncthreads();

    // ================= bitonic sort (desc) ==================================
    for (int k = 2; k <= 1024; k <<= 1) {
        for (int j = k >> 1; j > 0; j >>= 1) {
            int ixj = tid ^ j;
            if (ixj > tid) {
                unsigned long long a = keys[tid], b = keys[ixj];
                bool sw2 = ((tid & k) == 0) ? (a < b) : (a > b);
                if (sw2) { keys[tid] = b; keys[ixj] = a; }
            }
            __syncthreads();
        }
    }

    // ================= decode + clip ========================================
    const float imh = im_info[0], imw = im_info[1];
    if (tid < K) {
        int n = (int)(0xFFFFFFFFu - (unsigned)(keys[tid] & 0xFFFFFFFFull));
        int cell = n / A, a = n - cell * A;
        int hc = cell >> 5, wc = cell & 31;
        int a2 = (branch == 0) ? (a % 9) : a;
        int ri = a2 / 3, si = a2 % 3;
        float w = c_ws[ri] * c_sc[si], h = c_hs[ri] * c_sc[si];
        float lo[3], hi[3], mx[3];
        lo[0] = 7.5f - (w - 1.f) * 0.5f + 16.f * wc;
        hi[0] = 7.5f + (w - 1.f) * 0.5f + 16.f * wc;
        mx[0] = imw - 1.f;
        lo[1] = 7.5f - (h - 1.f) * 0.5f + 16.f * hc;
        hi[1] = 7.5f + (h - 1.f) * 0.5f + 16.f * hc;
        mx[1] = imh - 1.f;
        if (branch == 0) { lo[2] = 0.f; hi[2] = c_depth[a / 9] - 1.f; mx[2] = (float)(T_DIM - 1); }
        const float* dp = deltas + (size_t)n * (2 * nd);
        for (int d = 0; d < nd; d++) {
            float size = hi[d] - lo[d] + 1.f;
            float ctr = lo[d] + 0.5f * (size - 1.f);
            float pctr = dp[d] * size + ctr;
            float psize = expf(dp[nd + d]) * size;
            float pl = pctr - 0.5f * (psize - 1.f);
            float ph = pctr + 0.5f * (psize - 1.f);
            bx[tid][d]      = fminf(fmaxf(pl, 0.f), mx[d]);
            bx[tid][nd + d] = fminf(fmaxf(ph, 0.f), mx[d]);
        }
    }
    if (tid < 16) alive[tid] = (tid < 15) ? ~0ull : ((1ull << (K - 15 * 64)) - 1);
    __syncthreads();

    // ================= NMS (bitmask) ========================================
    float myb[6]; float myvol = 1.f;
    if (tid < K) {
        for (int d = 0; d < 6; d++) myb[d] = bx[tid][d];
        for (int d = 0; d < nd; d++) myvol *= (myb[nd + d] - myb[d] + 1.f);
    }
    for (int i = 0; i < POST_NMS; ++i) {
        if (tid < 64) {
            unsigned long long wvb = (tid < 16) ? alive[tid] : 0ull;
            int cand = wvb ? (tid * 64 + __ffsll(wvb) - 1) : 0x7fffffff;
#pragma unroll
            for (int off = 32; off; off >>= 1)
                cand = min(cand, __shfl_xor(cand, off));
            if (tid == 0) {
                int m = (cand == 0x7fffffff) ? 0 : cand;
                bcast = m; keep[i] = m;
            }
        }
        __syncthreads();
        int sel = bcast;
        bool s = false;
        if (tid < K) {
            float inter = 1.f, selvol = 1.f;
            for (int d = 0; d < nd; d++) {
                float slo = bx[sel][d], shi = bx[sel][nd + d];
                float l = fmaxf(slo, myb[d]);
                float hh = fminf(shi, myb[nd + d]);
                inter *= fmaxf(hh - l + 1.f, 0.f);
                selvol *= (shi - slo + 1.f);
            }
            float iou = inter / (selvol + myvol - inter);
            s = (iou > NMS_TH) || (tid == sel);
        }
        unsigned long long bal = __ballot(s);
        if (lane == 0 && bal) alive[wid] &= ~bal;
        __syncthreads();
    }

    // ================= write outputs ========================================
    if (tid < POST_NMS) {
        int k = keep[tid];
        if (branch == 0) {
            float* o = out + (size_t)tid * 7;
            o[0] = 0.f;
            for (int d = 0; d < 6; d++) o[1 + d] = bx[k][d];
        } else {
            float* o = out + 128 * 7 + (size_t)tid * 5;
            o[0] = 0.f;
            for (int d = 0; d < 4; d++) o[1 + d] = bx[k][d];
        }
    }
    if (branch == 0 && tid == 0) {
        out[1536] = 0.f; out[1537] = 0.f; out[1538] = 0.f; out[1539] = 0.f;
    }
}

// ---------------------------------------------------------------------------
extern "C" void kernel_launch(void* const* d_in, const int* in_sizes, int n_in,
                              void* d_out, int out_size, void* d_ws, size_t ws_size,
                              hipStream_t stream) {
    (void)in_sizes; (void)n_in; (void)out_size; (void)ws_size;
    const float* base_feat = (const float*)d_in[0];
    const float* im_info   = (const float*)d_in[1];
    const float* W_conv    = (const float*)d_in[4];
    const float* b_conv    = (const float*)d_in[5];
    const float* W_cls     = (const float*)d_in[6];
    const float* b_cls     = (const float*)d_in[7];
    const float* W_bbox    = (const float*)d_in[8];
    const float* b_bbox    = (const float*)d_in[9];
    const float* W_cls16   = (const float*)d_in[10];
    const float* b_cls16   = (const float*)d_in[11];
    const float* W_bbox16  = (const float*)d_in[12];
    const float* b_bbox16  = (const float*)d_in[13];
    float* out = (float*)d_out;

    // workspace: A0/A1/A2 (bf16 splits, dead after conv) alias L3
    char* ws = (char*)d_ws;
    const size_t AW = (size_t)27 * 512 * 256;
    short* A0 = (short*)ws;
    short* A1 = A0 + AW;
    short* A2 = A1 + AW;
    float* L3 = (float*)ws;
    size_t off = AW * 3 * sizeof(short);
    float* Wcomb  = (float*)(ws + off); off += (size_t)512 * 256 * 4;
    float* conv1  = (float*)(ws + off); off += (size_t)COUT * NVOX * 4;
    float* feat2  = (float*)(ws + off); off += (size_t)512 * HW * 4;
    float* L2     = (float*)(ws + off); off += (size_t)64 * HW * 4;
    float* sc3    = (float*)(ws + off); off += (size_t)27 * HW * 4;
    float* dl3    = (float*)(ws + off); off += (size_t)27 * HW * 6 * 4;
    float* sc2    = (float*)(ws + off); off += (size_t)9 * HW * 4;
    float* dl2    = (float*)(ws + off); off += (size_t)9 * HW * 4 * 4;

    k_split_w<<<13824, 256, 0, stream>>>(W_conv, A0, A1, A2);
    k_build_wcomb<<<512, 256, 0, stream>>>(W_cls, W_bbox, Wcomb);
    {
        dim3 g(NVOX / 128, COUT / 128);
        k_conv3d_mfma<<<g, 256, 0, stream>>>(base_feat, A0, A1, A2, b_conv, conv1);
    }
    {
        dim3 g(NVOX / 128, 2);
        k_gemm_logits3<<<g, 256, 0, stream>>>(conv1, Wcomb, L3);
    }
    k_sc3<<<(27 * HW + 255) / 256, 256, 0, stream>>>(L3, b_cls, sc3);
    k_dl3<<<(162 * HW + 255) / 256, 256, 0, stream>>>(L3, b_bbox, dl3);
    k_feat2<<<(512 * HW) / 256, 256, 0, stream>>>(conv1, feat2);
    k_gemm2d<<<(54 * HW) / 256, 256, 0, stream>>>(feat2, W_cls16, W_bbox16, L2);
    k_sc2<<<(9 * HW + 255) / 256, 256, 0, stream>>>(L2, b_cls16, sc2);
    k_dl2<<<(36 * HW + 255) / 256, 256, 0, stream>>>(L2, b_bbox16, dl2);
    k_proposal<<<2, 1024, 0, stream>>>(im_info, sc3, dl3, sc2, dl2, out);
}

// Round 12
// 973.257 us; speedup vs baseline: 1.3089x; 1.3089x over previous
//
#include <hip/hip_runtime.h>
#include <hip/hip_bf16.h>
#include <cfloat>
#include <cstdint>

// ---------------------------------------------------------------------------
// RPN pipeline (B=1): conv3d(256->512,3x3x3,SAME)+ReLU -> heads -> proposals
// Round-12: r10 conv structure (single A set, 24KB LDS, 2 blk/CU) +
// (1) bit-trick B split (r11-verified), (2) stage reorder: raw B(s+1) loads
// issue BEFORE compute, split AFTER compute -> split chain + B gather latency
// hidden under the 96-MFMA phase; COMPUTE waits only on A loads.
// r11 lesson: A register double-buffer (+96 VGPR) halved occupancy — reverted.
// ---------------------------------------------------------------------------

#define T_DIM 16
#define H_DIM 32
#define W_DIM 32
#define NVOX  (T_DIM*H_DIM*W_DIM)   // 16384
#define HW    (H_DIM*W_DIM)         // 1024
#define CIN   256
#define COUT  512
#define PRE_NMS 1000
#define POST_NMS 128
#define NMS_TH 0.7f

typedef __attribute__((ext_vector_type(8))) short v8s;
typedef __attribute__((ext_vector_type(4))) float v4f;
typedef __attribute__((ext_vector_type(4))) int v4i;

#define MFMA_B16(A,B,C) __builtin_amdgcn_mfma_f32_16x16x32_bf16(A,B,C,0,0,0)

__device__ __forceinline__ short f2bf(float x) {
    unsigned u = __float_as_uint(x);
    u += 0x7FFFu + ((u >> 16) & 1u);
    return (short)(u >> 16);
}
__device__ __forceinline__ float bf2f(short s) {
    return __uint_as_float(((unsigned)(unsigned short)s) << 16);
}

__constant__ float c_ws[3] = {23.f, 16.f, 11.f};
__constant__ float c_hs[3] = {12.f, 16.f, 22.f};
__constant__ float c_sc[3] = {4.f, 8.f, 16.f};
__constant__ float c_depth[3] = {16.f, 8.f, 4.f};

// ---------------------------------------------------------------------------
// Weight split, FRAGMENT-MAJOR: Af[((tap*32 + ko)*512 + o)*8 + c7], c=ko*8+c7.
__global__ void k_split_w(const float* __restrict__ W, short* __restrict__ A0,
                          short* __restrict__ A1, short* __restrict__ A2) {
    int i = blockIdx.x * 256 + threadIdx.x;   // over 27*32*512*8 = 3538944
    int c7 = i & 7;
    int o = (i >> 3) & 511;
    int ko = (i >> 12) & 31;
    int tap = i >> 17;
    int c = ko * 8 + c7;
    float x = W[(o * 256 + c) * 27 + tap];
    short h = f2bf(x); float r = x - bf2f(h);
    short m = f2bf(r); float r2 = r - bf2f(m);
    short l = f2bf(r2);
    A0[i] = h; A1[i] = m; A2[i] = l;
}

__global__ void k_build_wcomb(const float* __restrict__ Wcls, const float* __restrict__ Wbb,
                              float* __restrict__ Wc) {
    int i = blockIdx.x * 256 + threadIdx.x;   // over 512*256
    int o = i & 255;
    int c = i >> 8;
    float v = 0.f;
    if (o < 54) v = Wcls[o * 512 + c];
    else if (o < 216) v = Wbb[(o - 54) * 512 + c];
    Wc[i] = v;
}

// ---------------------------------------------------------------------------
// bit-trick split of 2 floats -> 3 packed bf16-pair ints (low = X0, high = X1)
// h = top16(x) [trunc]; r = x-h exact; m = top16(r); l = top16(r-m).
// residual <= 2^-24|x| (verified r11: absmax 0.0).
#define SPLIT2(X0, X1, OH, OM, OL) {                                          \
    unsigned u0_ = __float_as_uint(X0), u1_ = __float_as_uint(X1);            \
    OH = (int)__builtin_amdgcn_perm(u1_, u0_, 0x07060302u);                   \
    float h0_ = __uint_as_float(u0_ & 0xFFFF0000u);                           \
    float h1_ = __uint_as_float(u1_ & 0xFFFF0000u);                           \
    float r0_ = (X0) - h0_, r1_ = (X1) - h1_;                                 \
    unsigned v0_ = __float_as_uint(r0_), v1_ = __float_as_uint(r1_);          \
    OM = (int)__builtin_amdgcn_perm(v1_, v0_, 0x07060302u);                   \
    float m0_ = __uint_as_float(v0_ & 0xFFFF0000u);                           \
    float m1_ = __uint_as_float(v1_ & 0xFFFF0000u);                           \
    float s0_ = r0_ - m0_, s1_ = r1_ - m1_;                                   \
    OL = (int)__builtin_amdgcn_perm(__float_as_uint(s1_),                     \
                                    __float_as_uint(s0_), 0x07060302u);       \
}

#define CV_SHIFT(TAP) {                                                       \
    int kt_ = (TAP) / 9 - 1, kh_ = ((TAP) / 3) % 3 - 1, kw_ = (TAP) % 3 - 1;  \
    int tt_ = bt + kt_, hh_ = bh + kh_, ww_ = bw + kw_;                       \
    bVal = ((unsigned)tt_ < 16u) && ((unsigned)hh_ < 32u) && ((unsigned)ww_ < 32u); \
    bOff = bVal ? ((tt_ << 10) + (hh_ << 5) + ww_) : 0;                       \
}

// raw B loads for next stage (issued BEFORE compute; consumed after)
#define CV_LOAD_B_RAW(CK) {                                                   \
    const float* ip_ = I + ((size_t)((CK) + skh * 16) << 14) + bOff;          \
    bx0  = bVal ? ip_[0]        : 0.f;                                        \
    bx1  = bVal ? ip_[1 << 14]  : 0.f;                                        \
    bx2  = bVal ? ip_[2 << 14]  : 0.f;                                        \
    bx3  = bVal ? ip_[3 << 14]  : 0.f;                                        \
    bx4  = bVal ? ip_[4 << 14]  : 0.f;                                        \
    bx5  = bVal ? ip_[5 << 14]  : 0.f;                                        \
    bx6  = bVal ? ip_[6 << 14]  : 0.f;                                        \
    bx7  = bVal ? ip_[7 << 14]  : 0.f;                                        \
    bx8  = bVal ? ip_[8 << 14]  : 0.f;                                        \
    bx9  = bVal ? ip_[9 << 14]  : 0.f;                                        \
    bx10 = bVal ? ip_[10 << 14] : 0.f;                                        \
    bx11 = bVal ? ip_[11 << 14] : 0.f;                                        \
    bx12 = bVal ? ip_[12 << 14] : 0.f;                                        \
    bx13 = bVal ? ip_[13 << 14] : 0.f;                                        \
    bx14 = bVal ? ip_[14 << 14] : 0.f;                                        \
    bx15 = bVal ? ip_[15 << 14] : 0.f;                                        \
}

// split raw B into pb* (runs AFTER compute; inputs arrived during MFMA phase)
#define CV_SPLIT_B() {                                                        \
    int h01,h23,h45,h67,m01,m23,m45,m67,l01,l23,l45,l67;                      \
    SPLIT2(bx0,  bx1,  h01, m01, l01);                                        \
    SPLIT2(bx2,  bx3,  h23, m23, l23);                                        \
    SPLIT2(bx4,  bx5,  h45, m45, l45);                                        \
    SPLIT2(bx6,  bx7,  h67, m67, l67);                                        \
    pbh0 = (v4i){h01, h23, h45, h67};                                         \
    pbm0 = (v4i){m01, m23, m45, m67};                                         \
    pbl0 = (v4i){l01, l23, l45, l67};                                         \
    SPLIT2(bx8,  bx9,  h01, m01, l01);                                        \
    SPLIT2(bx10, bx11, h23, m23, l23);                                        \
    SPLIT2(bx12, bx13, h45, m45, l45);                                        \
    SPLIT2(bx14, bx15, h67, m67, l67);                                        \
    pbh1 = (v4i){h01, h23, h45, h67};                                         \
    pbm1 = (v4i){m01, m23, m45, m67};                                         \
    pbl1 = (v4i){l01, l23, l45, l67};                                         \
}

#define LOAD_ASET(S) {                                                        \
    const size_t aB_ = (((size_t)((S) >> 3) * 32 + (((S) & 7) << 2)) << 12) + aLane; \
    ah0 = *(const v8s*)(A0 + aB_);       ah1 = *(const v8s*)(A0 + aB_ + 128); \
    ah2 = *(const v8s*)(A0 + aB_ + 256); ah3 = *(const v8s*)(A0 + aB_ + 384); \
    am0 = *(const v8s*)(A1 + aB_);       am1 = *(const v8s*)(A1 + aB_ + 128); \
    am2 = *(const v8s*)(A1 + aB_ + 256); am3 = *(const v8s*)(A1 + aB_ + 384); \
    al0 = *(const v8s*)(A2 + aB_);       al1 = *(const v8s*)(A2 + aB_ + 128); \
    al2 = *(const v8s*)(A2 + aB_ + 256); al3 = *(const v8s*)(A2 + aB_ + 384); \
}

#define COMPUTE() {                                                           \
    _Pragma("unroll")                                                         \
    for (int j = 0; j < 4; ++j) {                                             \
        v8s bb = *(const v8s*)(&Bsh[0][uB + j * 16]);                         \
        v8s bm = *(const v8s*)(&Bsh[1][uB + j * 16]);                         \
        v8s bl = *(const v8s*)(&Bsh[2][uB + j * 16]);                         \
        v4f a;                                                                \
        a = acc[0][j];                                                        \
        a = MFMA_B16(ah0, bb, a); a = MFMA_B16(ah0, bm, a);                   \
        a = MFMA_B16(am0, bb, a); a = MFMA_B16(ah0, bl, a);                   \
        a = MFMA_B16(am0, bm, a); a = MFMA_B16(al0, bb, a);                   \
        acc[0][j] = a;                                                        \
        a = acc[1][j];                                                        \
        a = MFMA_B16(ah1, bb, a); a = MFMA_B16(ah1, bm, a);                   \
        a = MFMA_B16(am1, bb, a); a = MFMA_B16(ah1, bl, a);                   \
        a = MFMA_B16(am1, bm, a); a = MFMA_B16(al1, bb, a);                   \
        acc[1][j] = a;                                                        \
        a = acc[2][j];                                                        \
        a = MFMA_B16(ah2, bb, a); a = MFMA_B16(ah2, bm, a);                   \
        a = MFMA_B16(am2, bb, a); a = MFMA_B16(ah2, bl, a);                   \
        a = MFMA_B16(am2, bm, a); a = MFMA_B16(al2, bb, a);                   \
        acc[2][j] = a;                                                        \
        a = acc[3][j];                                                        \
        a = MFMA_B16(ah3, bb, a); a = MFMA_B16(ah3, bm, a);                   \
        a = MFMA_B16(am3, bb, a); a = MFMA_B16(ah3, bl, a);                   \
        a = MFMA_B16(am3, bm, a); a = MFMA_B16(al3, bb, a);                   \
        acc[3][j] = a;                                                        \
    }                                                                         \
}

// MFMA conv3d: 128x128 block tile, 4 waves in 2x2 (each 64o x 64v), BK=32,
// B single-buffer LDS (r10 layout), A direct global fragments (single set).
__global__ __launch_bounds__(256) void k_conv3d_mfma(
        const float* __restrict__ I, const short* __restrict__ A0,
        const short* __restrict__ A1, const short* __restrict__ A2,
        const float* __restrict__ bias, float* __restrict__ O) {
    __shared__ v4i Bsh[3][512];   // 24 KB
    const int tid = threadIdx.x;
    const int o0 = blockIdx.y * 128;
    const int v0 = blockIdx.x * 128;
    const int lane = tid & 63;
    const int wv = tid >> 6;
    const int quad = lane >> 4, m16 = lane & 15;
    const int wo = (wv >> 1) * 64;        // wave o-origin within tile
    const int wvx = (wv & 1) * 64;        // wave v-origin within tile

    // B staging: row sa_o = tid>>1 (0..127), k-half skh = tid&1
    const int sa_o = tid >> 1, skh = tid & 1;
    const int uW0 = (skh * 2) * 128 + sa_o;
    const int uW1 = (skh * 2 + 1) * 128 + sa_o;

    const int vbase = v0 + sa_o;
    const int bt = vbase >> 10, bh = (vbase >> 5) & 31, bw = vbase & 31;

    // B fragment read base: [quad*128 + wvx + j*16 + m16]
    const int uB = quad * 128 + wvx + m16;

    // A fragment global base offset (shorts): lane part
    const size_t aLane = ((size_t)(o0 + wo + m16) << 3) + ((size_t)quad << 12);

    v4f acc[4][4];
#pragma unroll
    for (int i = 0; i < 4; i++)
#pragma unroll
        for (int j = 0; j < 4; j++) acc[i][j] = (v4f){0.f, 0.f, 0.f, 0.f};

    int bOff, bVal;
    v4i pbh0, pbh1, pbm0, pbm1, pbl0, pbl1;
    v8s ah0, ah1, ah2, ah3, am0, am1, am2, am3, al0, al1, al2, al3;
    float bx0, bx1, bx2, bx3, bx4, bx5, bx6, bx7;
    float bx8, bx9, bx10, bx11, bx12, bx13, bx14, bx15;

    // prologue: stage-0 B split ready before loop
    CV_SHIFT(0);
    CV_LOAD_B_RAW(0);
    CV_SPLIT_B();

    for (int s = 0; s < 216; ++s) {       // 27 taps * 8 ck-steps (BK=32)
        __syncthreads();
        Bsh[0][uW0] = pbh0; Bsh[0][uW1] = pbh1;
        Bsh[1][uW0] = pbm0; Bsh[1][uW1] = pbm1;
        Bsh[2][uW0] = pbl0; Bsh[2][uW1] = pbl1;
        __syncthreads();
        LOAD_ASET(s);                     // A(s): compute waits only on these
        {
            int s1 = s + 1;
            if (s1 < 216) {
                if ((s1 & 7) == 0) CV_SHIFT(s1 >> 3);
                CV_LOAD_B_RAW((s1 & 7) << 5);   // raw loads in flight during MFMA
            }
        }
        COMPUTE();
        if (s + 1 < 216) CV_SPLIT_B();    // split after compute: inputs arrived
    }

    // epilogue: per 16x16 tile, col = m16 (v), row = quad*4 + reg (o)
#pragma unroll
    for (int i = 0; i < 4; ++i) {
#pragma unroll
        for (int r = 0; r < 4; ++r) {
            int o = o0 + wo + i * 16 + quad * 4 + r;
            float bo = bias[o];
            float* dst = O + (size_t)o * NVOX + v0 + wvx + m16;
#pragma unroll
            for (int j = 0; j < 4; ++j)
                dst[j * 16] = fmaxf(acc[i][j][r] + bo, 0.f);
        }
    }
}

// ---------------------------------------------------------------------------
// logits3 GEMM: L[o][v] = sum_c Wc[c][o] * conv1[c][v], M=256 (padded), K=512, N=16384
__global__ __launch_bounds__(256) void k_gemm_logits3(const float* __restrict__ conv1,
                                                      const float* __restrict__ Wc,
                                                      float* __restrict__ L) {
    __shared__ float As[16][128];
    __shared__ float Bs[16][128];
    const int tid = threadIdx.x;
    const int o0 = blockIdx.y * 128;
    const int v0 = blockIdx.x * 128;
    const int ty = tid >> 4, tx = tid & 15;

    float acc[8][8];
#pragma unroll
    for (int i = 0; i < 8; i++)
#pragma unroll
        for (int j = 0; j < 8; j++) acc[i][j] = 0.f;

    for (int ck = 0; ck < 512; ck += 16) {
        __syncthreads();
#pragma unroll
        for (int r = 0; r < 2; ++r) {
            int f = tid + r * 256;
            int c_l = f >> 5, o4 = (f & 31) << 2;
            *(float4*)(&As[c_l][o4]) = *(const float4*)(Wc + ((size_t)(ck + c_l) << 8) + o0 + o4);
        }
#pragma unroll
        for (int r = 0; r < 2; ++r) {
            int f = tid + r * 256;
            int c_l = f >> 5, v4 = (f & 31) << 2;
            *(float4*)(&Bs[c_l][v4]) = *(const float4*)(conv1 + ((size_t)(ck + c_l) << 14) + v0 + v4);
        }
        __syncthreads();
#pragma unroll
        for (int k = 0; k < 16; ++k) {
            float a[8], b[8];
            *(float4*)(a)     = *(const float4*)(&As[k][ty * 4]);
            *(float4*)(a + 4) = *(const float4*)(&As[k][64 + ty * 4]);
            *(float4*)(b)     = *(const float4*)(&Bs[k][tx * 4]);
            *(float4*)(b + 4) = *(const float4*)(&Bs[k][64 + tx * 4]);
#pragma unroll
            for (int i = 0; i < 8; i++)
#pragma unroll
                for (int j = 0; j < 8; j++)
                    acc[i][j] = fmaf(a[i], b[j], acc[i][j]);
        }
    }
#pragma unroll
    for (int i = 0; i < 8; i++) {
        int orow = (i < 4) ? (ty * 4 + i) : (64 + ty * 4 + (i - 4));
        float* dst = L + (size_t)(o0 + orow) * NVOX + v0;
        *(float4*)(dst + tx * 4)      = *(const float4*)(&acc[i][0]);
        *(float4*)(dst + 64 + tx * 4) = *(const float4*)(&acc[i][4]);
    }
}

// ---------------------------------------------------------------------------
__global__ void k_sc3(const float* __restrict__ L, const float* __restrict__ b_cls,
                      float* __restrict__ sc3) {
    int i = blockIdx.x * 256 + threadIdx.x;   // 27648
    if (i >= 27 * HW) return;
    int a = i >> 10, hw = i & 1023;
    float b0 = b_cls[a], b1 = b_cls[27 + a];
    const float* L0 = L + (size_t)a * NVOX + hw;
    const float* L1 = L + (size_t)(27 + a) * NVOX + hw;
    float s = 0.f;
    for (int t = 0; t < T_DIM; t++) {
        float x0 = L0[t * HW] + b0, x1 = L1[t * HW] + b1;
        float m = fmaxf(x0, x1);
        float e0 = expf(x0 - m), e1 = expf(x1 - m);
        s += e1 / (e0 + e1);
    }
    sc3[hw * 27 + a] = s * (1.f / 16.f);
}

__global__ void k_dl3(const float* __restrict__ L, const float* __restrict__ b_bbox,
                      float* __restrict__ dl3) {
    int i = blockIdx.x * 256 + threadIdx.x;   // 165888
    if (i >= 162 * HW) return;
    int ch = i >> 10, hw = i & 1023;
    const float* Lr = L + (size_t)(54 + ch) * NVOX + hw;
    float s = 0.f;
    for (int t = 0; t < T_DIM; t++) s += Lr[t * HW];
    s = s * (1.f / 16.f) + b_bbox[ch];
    int a = ch / 6, d = ch - a * 6;
    dl3[((size_t)hw * 27 + a) * 6 + d] = s;
}

__global__ void k_feat2(const float* __restrict__ conv1, float* __restrict__ feat2) {
    int i = blockIdx.x * 256 + threadIdx.x;   // 524288
    int c = i >> 10, hw = i & 1023;
    const float* src = conv1 + (size_t)c * NVOX + hw;
    float s = 0.f;
    for (int t = 0; t < T_DIM; t++) s += src[t * HW];
    feat2[i] = s * (1.f / 16.f);
}

__global__ void k_gemm2d(const float* __restrict__ feat2, const float* __restrict__ Wcls16,
                         const float* __restrict__ Wbb16, float* __restrict__ L2) {
    int g = blockIdx.x * 256 + threadIdx.x;   // 55296
    int o = g >> 10, hw = g & 1023;
    const float* wrow = (o < 18) ? (Wcls16 + (size_t)o * 512) : (Wbb16 + (size_t)(o - 18) * 512);
    float s = 0.f;
    for (int c = 0; c < 512; c++) s = fmaf(wrow[c], feat2[(size_t)c * HW + hw], s);
    L2[(size_t)o * HW + hw] = s;
}

__global__ void k_sc2(const float* __restrict__ L2, const float* __restrict__ b_cls16,
                      float* __restrict__ sc2) {
    int i = blockIdx.x * 256 + threadIdx.x;   // 9216
    if (i >= 9 * HW) return;
    int a = i >> 10, hw = i & 1023;
    float x0 = L2[(size_t)a * HW + hw] + b_cls16[a];
    float x1 = L2[(size_t)(9 + a) * HW + hw] + b_cls16[9 + a];
    float m = fmaxf(x0, x1);
    float e0 = expf(x0 - m), e1 = expf(x1 - m);
    sc2[hw * 9 + a] = e1 / (e0 + e1);
}

__global__ void k_dl2(const float* __restrict__ L2, const float* __restrict__ b_bbox16,
                      float* __restrict__ dl2) {
    int i = blockIdx.x * 256 + threadIdx.x;   // 36864
    if (i >= 36 * HW) return;
    int ch = i >> 10, hw = i & 1023;
    float v = L2[(size_t)(18 + ch) * HW + hw] + b_bbox16[ch];
    int a = ch >> 2, d = ch & 3;
    dl2[((size_t)hw * 9 + a) * 4 + d] = v;
}

// ---------------------------------------------------------------------------
__device__ __forceinline__ unsigned mapf(float f) {
    unsigned u = __float_as_uint(f);
    return (u & 0x80000000u) ? ~u : (u | 0x80000000u);
}

__global__ __launch_bounds__(1024) void k_proposal(const float* __restrict__ im_info,
                                                   const float* __restrict__ sc3,
                                                   const float* __restrict__ dl3,
                                                   const float* __restrict__ sc2,
                                                   const float* __restrict__ dl2,
                                                   float* __restrict__ out) {
    const int branch = blockIdx.x;
    const int tid = threadIdx.x;
    const int A = (branch == 0) ? 27 : 9;
    const int nd = (branch == 0) ? 3 : 2;
    const float* scores = (branch == 0) ? sc3 : sc2;
    const float* deltas = (branch == 0) ? dl3 : dl2;
    const int K = PRE_NMS;
    const int ept = A;
    const int base = tid * ept;

    __shared__ unsigned hist[256];
    __shared__ unsigned long long keys[1024];
    __shared__ float bx[PRE_NMS][6];
    __shared__ int keep[POST_NMS];
    __shared__ unsigned wsum[16];
    __shared__ unsigned long long alive[16];
    __shared__ int sh_b, sh_next, bcast;

    // ================= radix-select =========================================
    unsigned prefix = 0;
    int rank = K;
    for (int shift = 24; shift >= 0; shift -= 8) {
        if (tid < 256) hist[tid] = 0;
        __syncthreads();
        const unsigned mask_hi = (shift == 24) ? 0u : (0xFFFFFFFFu << (shift + 8));
        for (int j = 0; j < ept; j++) {
            unsigned m = mapf(scores[base + j]);
            if ((m & mask_hi) == prefix)
                atomicAdd(&hist[(m >> shift) & 255], 1u);
        }
        __syncthreads();
        for (int d = 1; d < 256; d <<= 1) {
            unsigned add = 0;
            if (tid < 256 && tid + d < 256) add = hist[tid + d];
            __syncthreads();
            if (tid < 256) hist[tid] += add;
            __syncthreads();
        }
        if (tid < 256) {
            bool win = (hist[tid] >= (unsigned)rank) &&
                       (tid == 255 || hist[tid + 1] < (unsigned)rank);
            if (win) { sh_b = tid; sh_next = (tid == 255) ? 0 : (int)hist[tid + 1]; }
        }
        __syncthreads();
        prefix |= (unsigned)sh_b << shift;
        rank -= sh_next;
        __syncthreads();
    }
    const unsigned tau = prefix;

    // ================= compaction ===========================================
    int gt_c = 0, eq_c = 0;
    for (int j = 0; j < ept; j++) {
        unsigned m = mapf(scores[base + j]);
        gt_c += (m > tau);
        eq_c += (m == tau);
    }
    unsigned cnt = ((unsigned)gt_c << 16) | (unsigned)eq_c;
    const int lane = tid & 63, wid = tid >> 6;
    unsigned x = cnt;
    for (int d = 1; d < 64; d <<= 1) {
        unsigned y = __shfl_up(x, d);
        if (lane >= d) x += y;
    }
    if (lane == 63) wsum[wid] = x;
    __syncthreads();
    if (wid == 0) {
        unsigned w = (lane < 16) ? wsum[lane] : 0;
        for (int d = 1; d < 16; d <<= 1) {
            unsigned y = __shfl_up(w, d);
            if (lane >= d) w += y;
        }
        if (lane < 16) wsum[lane] = w;
    }
    __syncthreads();
    unsigned excl = x - cnt + (wid ? wsum[wid - 1] : 0);
    const int c1 = (int)(wsum[15] >> 16);
    int gi = (int)(excl >> 16);
    int ei = (int)(excl & 0xFFFFu);
    for (int j = 0; j < ept; j++) {
        int idx = base + j;
        unsigned m = mapf(scores[idx]);
        unsigned long long key = ((unsigned long long)m << 32) |
                                 (unsigned)(0xFFFFFFFFu - (unsigned)idx);
        if (m > tau) {
            keys[gi++] = key;
        } else if (m == tau) {
            if (c1 + ei < K) keys[c1 + ei] = key;
            ei++;
        }
    }
    if (tid < 1024 - K) keys[K + tid] = 0;
    __syncthreads();

    // ================= bitonic sort (desc) ==================================
    for (int k = 2; k <= 1024; k <<= 1) {
        for (int j = k >> 1; j > 0; j >>= 1) {
            int ixj = tid ^ j;
            if (ixj > tid) {
                unsigned long long a = keys[tid], b = keys[ixj];
                bool sw2 = ((tid & k) == 0) ? (a < b) : (a > b);
                if (sw2) { keys[tid] = b; keys[ixj] = a; }
            }
            __syncthreads();
        }
    }

    // ================= decode + clip ========================================
    const float imh = im_info[0], imw = im_info[1];
    if (tid < K) {
        int n = (int)(0xFFFFFFFFu - (unsigned)(keys[tid] & 0xFFFFFFFFull));
        int cell = n / A, a = n - cell * A;
        int hc = cell >> 5, wc = cell & 31;
        int a2 = (branch == 0) ? (a % 9) : a;
        int ri = a2 / 3, si = a2 % 3;
        float w = c_ws[ri] * c_sc[si], h = c_hs[ri] * c_sc[si];
        float lo[3], hi[3], mx[3];
        lo[0] = 7.5f - (w - 1.f) * 0.5f + 16.f * wc;
        hi[0] = 7.5f + (w - 1.f) * 0.5f + 16.f * wc;
        mx[0] = imw - 1.f;
        lo[1] = 7.5f - (h - 1.f) * 0.5f + 16.f * hc;
        hi[1] = 7.5f + (h - 1.f) * 0.5f + 16.f * hc;
        mx[1] = imh - 1.f;
        if (branch == 0) { lo[2] = 0.f; hi[2] = c_depth[a / 9] - 1.f; mx[2] = (float)(T_DIM - 1); }
        const float* dp = deltas + (size_t)n * (2 * nd);
        for (int d = 0; d < nd; d++) {
            float size = hi[d] - lo[d] + 1.f;
            float ctr = lo[d] + 0.5f * (size - 1.f);
            float pctr = dp[d] * size + ctr;
            float psize = expf(dp[nd + d]) * size;
            float pl = pctr - 0.5f * (psize - 1.f);
            float ph = pctr + 0.5f * (psize - 1.f);
            bx[tid][d]      = fminf(fmaxf(pl, 0.f), mx[d]);
            bx[tid][nd + d] = fminf(fmaxf(ph, 0.f), mx[d]);
        }
    }
    if (tid < 16) alive[tid] = (tid < 15) ? ~0ull : ((1ull << (K - 15 * 64)) - 1);
    __syncthreads();

    // ================= NMS (bitmask) ========================================
    float myb[6]; float myvol = 1.f;
    if (tid < K) {
        for (int d = 0; d < 6; d++) myb[d] = bx[tid][d];
        for (int d = 0; d < nd; d++) myvol *= (myb[nd + d] - myb[d] + 1.f);
    }
    for (int i = 0; i < POST_NMS; ++i) {
        if (tid < 64) {
            unsigned long long wvb = (tid < 16) ? alive[tid] : 0ull;
            int cand = wvb ? (tid * 64 + __ffsll(wvb) - 1) : 0x7fffffff;
#pragma unroll
            for (int off = 32; off; off >>= 1)
                cand = min(cand, __shfl_xor(cand, off));
            if (tid == 0) {
                int m = (cand == 0x7fffffff) ? 0 : cand;
                bcast = m; keep[i] = m;
            }
        }
        __syncthreads();
        int sel = bcast;
        bool s = false;
        if (tid < K) {
            float inter = 1.f, selvol = 1.f;
            for (int d = 0; d < nd; d++) {
                float slo = bx[sel][d], shi = bx[sel][nd + d];
                float l = fmaxf(slo, myb[d]);
                float hh = fminf(shi, myb[nd + d]);
                inter *= fmaxf(hh - l + 1.f, 0.f);
                selvol *= (shi - slo + 1.f);
            }
            float iou = inter / (selvol + myvol - inter);
            s = (iou > NMS_TH) || (tid == sel);
        }
        unsigned long long bal = __ballot(s);
        if (lane == 0 && bal) alive[wid] &= ~bal;
        __syncthreads();
    }

    // ================= write outputs ========================================
    if (tid < POST_NMS) {
        int k = keep[tid];
        if (branch == 0) {
            float* o = out + (size_t)tid * 7;
            o[0] = 0.f;
            for (int d = 0; d < 6; d++) o[1 + d] = bx[k][d];
        } else {
            float* o = out + 128 * 7 + (size_t)tid * 5;
            o[0] = 0.f;
            for (int d = 0; d < 4; d++) o[1 + d] = bx[k][d];
        }
    }
    if (branch == 0 && tid == 0) {
        out[1536] = 0.f; out[1537] = 0.f; out[1538] = 0.f; out[1539] = 0.f;
    }
}

// ---------------------------------------------------------------------------
extern "C" void kernel_launch(void* const* d_in, const int* in_sizes, int n_in,
                              void* d_out, int out_size, void* d_ws, size_t ws_size,
                              hipStream_t stream) {
    (void)in_sizes; (void)n_in; (void)out_size; (void)ws_size;
    const float* base_feat = (const float*)d_in[0];
    const float* im_info   = (const float*)d_in[1];
    const float* W_conv    = (const float*)d_in[4];
    const float* b_conv    = (const float*)d_in[5];
    const float* W_cls     = (const float*)d_in[6];
    const float* b_cls     = (const float*)d_in[7];
    const float* W_bbox    = (const float*)d_in[8];
    const float* b_bbox    = (const float*)d_in[9];
    const float* W_cls16   = (const float*)d_in[10];
    const float* b_cls16   = (const float*)d_in[11];
    const float* W_bbox16  = (const float*)d_in[12];
    const float* b_bbox16  = (const float*)d_in[13];
    float* out = (float*)d_out;

    // workspace: A0/A1/A2 (bf16 splits, dead after conv) alias L3
    char* ws = (char*)d_ws;
    const size_t AW = (size_t)27 * 512 * 256;
    short* A0 = (short*)ws;
    short* A1 = A0 + AW;
    short* A2 = A1 + AW;
    float* L3 = (float*)ws;
    size_t off = AW * 3 * sizeof(short);
    float* Wcomb  = (float*)(ws + off); off += (size_t)512 * 256 * 4;
    float* conv1  = (float*)(ws + off); off += (size_t)COUT * NVOX * 4;
    float* feat2  = (float*)(ws + off); off += (size_t)512 * HW * 4;
    float* L2     = (float*)(ws + off); off += (size_t)64 * HW * 4;
    float* sc3    = (float*)(ws + off); off += (size_t)27 * HW * 4;
    float* dl3    = (float*)(ws + off); off += (size_t)27 * HW * 6 * 4;
    float* sc2    = (float*)(ws + off); off += (size_t)9 * HW * 4;
    float* dl2    = (float*)(ws + off); off += (size_t)9 * HW * 4 * 4;

    k_split_w<<<13824, 256, 0, stream>>>(W_conv, A0, A1, A2);
    k_build_wcomb<<<512, 256, 0, stream>>>(W_cls, W_bbox, Wcomb);
    {
        dim3 g(NVOX / 128, COUT / 128);
        k_conv3d_mfma<<<g, 256, 0, stream>>>(base_feat, A0, A1, A2, b_conv, conv1);
    }
    {
        dim3 g(NVOX / 128, 2);
        k_gemm_logits3<<<g, 256, 0, stream>>>(conv1, Wcomb, L3);
    }
    k_sc3<<<(27 * HW + 255) / 256, 256, 0, stream>>>(L3, b_cls, sc3);
    k_dl3<<<(162 * HW + 255) / 256, 256, 0, stream>>>(L3, b_bbox, dl3);
    k_feat2<<<(512 * HW) / 256, 256, 0, stream>>>(conv1, feat2);
    k_gemm2d<<<(54 * HW) / 256, 256, 0, stream>>>(feat2, W_cls16, W_bbox16, L2);
    k_sc2<<<(9 * HW + 255) / 256, 256, 0, stream>>>(L2, b_cls16, sc2);
    k_dl2<<<(36 * HW + 255) / 256, 256, 0, stream>>>(L2, b_bbox16, dl2);
    k_proposal<<<2, 1024, 0, stream>>>(im_info, sc3, dl3, sc2, dl2, out);
}